// Round 1
// baseline (1248.093 us; speedup 1.0000x reference)
//
#include <hip/hip_runtime.h>
#include <math.h>

#define NN 50000
#define EPSM 1e-7f
#define BN_EPS 1e-5f

// ---- monotone float<->uint encoding for atomicMax on floats ----
__device__ __forceinline__ unsigned enc_f(float f){
  unsigned u = __float_as_uint(f);
  return (u & 0x80000000u) ? ~u : (u | 0x80000000u);
}
__device__ __forceinline__ float dec_f(unsigned e){
  unsigned u = (e & 0x80000000u) ? (e ^ 0x80000000u) : ~e;
  return __uint_as_float(u);
}

__global__ __launch_bounds__(256) void zero_kernel(float4* p, int n4){
  int i = blockIdx.x * 256 + threadIdx.x;
  if (i < n4) p[i] = make_float4(0.f, 0.f, 0.f, 0.f);
}

// pass 1: per-(dst,channel) max of logits = t * (relu(x[src]) + eps)
__global__ __launch_bounds__(256) void seg_max_kernel(
    const float* __restrict__ x, const int* __restrict__ src,
    const int* __restrict__ dst, const float* __restrict__ tptr, int layer,
    unsigned* __restrict__ segmax, int E){
  int idx = blockIdx.x * 256 + threadIdx.x;
  int e = idx >> 6;
  if (e >= E) return;
  int c = idx & 63;
  int s = src[e], d = dst[e];
  float t = tptr[layer];
  float m = fmaxf(x[s * 64 + c], 0.f) + EPSM;
  atomicMax(&segmax[d * 64 + c], enc_f(m * t));
}

// pass 2: den += exp(logit - max); num += m * exp(logit - max)
__global__ __launch_bounds__(256) void seg_sum_kernel(
    const float* __restrict__ x, const int* __restrict__ src,
    const int* __restrict__ dst, const float* __restrict__ tptr, int layer,
    const unsigned* __restrict__ segmax, float* __restrict__ den,
    float* __restrict__ num, int E){
  int idx = blockIdx.x * 256 + threadIdx.x;
  int e = idx >> 6;
  if (e >= E) return;
  int c = idx & 63;
  int s = src[e], d = dst[e];
  float t = tptr[layer];
  float m = fmaxf(x[s * 64 + c], 0.f) + EPSM;
  float lg = m * t;
  float mx = dec_f(segmax[d * 64 + c]);
  float ex = __expf(lg - mx);
  atomicAdd(&den[d * 64 + c], ex);
  atomicAdd(&num[d * 64 + c], m * ex);
}

// h0 = num/(den+1e-16) + x   (handles empty segments: 0/(0+1e-16)=0)
__global__ __launch_bounds__(256) void combine_kernel(
    const float* __restrict__ x, const float* __restrict__ den,
    const float* __restrict__ num, float* __restrict__ h0, int n){
  int i = blockIdx.x * 256 + threadIdx.x;
  if (i < n) h0[i] = num[i] / (den[i] + 1e-16f) + x[i];
}

// h1[N,128] = h0[N,64] @ W1[64,128] + b1 ; 64-row x 128-col tile per block
__global__ __launch_bounds__(256) void gemm1_kernel(
    const float* __restrict__ h0, const float* __restrict__ W1,
    const float* __restrict__ b1, float* __restrict__ h1, int N){
  __shared__ float a_lds[64 * 68];    // 64 rows x 64 k, stride 68 (16B-aligned pad)
  __shared__ float w_lds[64 * 128];   // 64 k x 128 cols
  int t = threadIdx.x;
  const float4* wg = (const float4*)W1;
  float4* wl = (float4*)w_lds;
#pragma unroll
  for (int i = 0; i < 8; ++i) wl[t + 256 * i] = wg[t + 256 * i];
  int row0 = blockIdx.x * 64;
#pragma unroll
  for (int i = 0; i < 4; ++i){
    int li = t + 256 * i;        // 0..1023 float4s of A-tile
    int r = li >> 4, q = li & 15;
    int gr = row0 + r;
    float4 v = make_float4(0.f, 0.f, 0.f, 0.f);
    if (gr < N) v = ((const float4*)h0)[gr * 16 + q];
    *(float4*)&a_lds[r * 68 + q * 4] = v;
  }
  __syncthreads();
  int tc = t & 31, tr = t >> 5;          // tc: 4-col group; tr: 8-row group
  float4 bias = ((const float4*)b1)[tc];
  float acc[8][4];
#pragma unroll
  for (int r = 0; r < 8; ++r){
    acc[r][0] = bias.x; acc[r][1] = bias.y; acc[r][2] = bias.z; acc[r][3] = bias.w;
  }
  for (int k = 0; k < 64; k += 4){
    float4 w0 = *(const float4*)&w_lds[(k + 0) * 128 + tc * 4];
    float4 w1 = *(const float4*)&w_lds[(k + 1) * 128 + tc * 4];
    float4 w2 = *(const float4*)&w_lds[(k + 2) * 128 + tc * 4];
    float4 w3 = *(const float4*)&w_lds[(k + 3) * 128 + tc * 4];
#pragma unroll
    for (int r = 0; r < 8; ++r){
      float4 a = *(const float4*)&a_lds[(tr * 8 + r) * 68 + k];
      acc[r][0] += a.x * w0.x + a.y * w1.x + a.z * w2.x + a.w * w3.x;
      acc[r][1] += a.x * w0.y + a.y * w1.y + a.z * w2.y + a.w * w3.y;
      acc[r][2] += a.x * w0.z + a.y * w1.z + a.z * w2.z + a.w * w3.z;
      acc[r][3] += a.x * w0.w + a.y * w1.w + a.z * w2.w + a.w * w3.w;
    }
  }
#pragma unroll
  for (int r = 0; r < 8; ++r){
    int gr = row0 + tr * 8 + r;
    if (gr < N)
      *(float4*)&h1[gr * 128 + tc * 4] =
          make_float4(acc[r][0], acc[r][1], acc[r][2], acc[r][3]);
  }
}

// per-channel sum and sumsq of h1 (column = threadIdx.x, coalesced rows)
__global__ __launch_bounds__(128) void bn_stats_kernel(
    const float* __restrict__ h1, float* __restrict__ bn, int N){
  int c = threadIdx.x;
  float s = 0.f, s2 = 0.f;
  for (int r = blockIdx.x; r < N; r += gridDim.x){
    float v = h1[r * 128 + c];
    s += v; s2 += v * v;
  }
  atomicAdd(&bn[c], s);
  atomicAdd(&bn[128 + c], s2);
}

__global__ void bn_final_kernel(float* __restrict__ bn,
                                const float* __restrict__ gamma,
                                const float* __restrict__ beta, int layer, int N){
  int c = threadIdx.x;   // 128 threads
  float mean = bn[c] / (float)N;
  float var = bn[128 + c] / (float)N - mean * mean;
  var = fmaxf(var, 0.f);
  float sc = gamma[layer * 128 + c] / sqrtf(var + BN_EPS);
  bn[256 + c] = sc;                                  // scale
  bn[384 + c] = beta[layer * 128 + c] - mean * sc;   // shift
}

// xout[N,64] = relu( relu(BN(h1)) @ W2[128,64] + b2 ) ; BN+relu fused into staging
__global__ __launch_bounds__(256) void gemm2_kernel(
    const float* __restrict__ h1, const float* __restrict__ bn,
    const float* __restrict__ W2, const float* __restrict__ b2,
    float* __restrict__ xout, int N){
  __shared__ float a_lds[64 * 132];   // 64 rows x 128 k, stride 132
  __shared__ float w_lds[128 * 68];   // 128 k x 64 cols, stride 68
  int t = threadIdx.x;
  const float4* wg = (const float4*)W2;
#pragma unroll
  for (int i = 0; i < 8; ++i){
    int li = t + 256 * i;        // 0..2047
    int k = li >> 4, q = li & 15;
    *(float4*)&w_lds[k * 68 + q * 4] = wg[li];
  }
  int row0 = blockIdx.x * 64;
  const float* scale = bn + 256;
  const float* shift = bn + 384;
#pragma unroll
  for (int i = 0; i < 8; ++i){
    int li = t + 256 * i;        // 0..2047 float4s of A-tile
    int r = li >> 5, q = li & 31;
    int gr = row0 + r;
    float4 v = make_float4(0.f, 0.f, 0.f, 0.f);
    if (gr < N) v = ((const float4*)h1)[gr * 32 + q];
    float4 sc = ((const float4*)scale)[q];
    float4 sh = ((const float4*)shift)[q];
    v.x = fmaxf(v.x * sc.x + sh.x, 0.f);
    v.y = fmaxf(v.y * sc.y + sh.y, 0.f);
    v.z = fmaxf(v.z * sc.z + sh.z, 0.f);
    v.w = fmaxf(v.w * sc.w + sh.w, 0.f);
    *(float4*)&a_lds[r * 132 + q * 4] = v;
  }
  __syncthreads();
  int tc = t & 15, tr = t >> 4;        // tc: 4-col group (64 cols); tr: 4-row group
  float4 bias = ((const float4*)b2)[tc];
  float acc[4][4];
#pragma unroll
  for (int r = 0; r < 4; ++r){
    acc[r][0] = bias.x; acc[r][1] = bias.y; acc[r][2] = bias.z; acc[r][3] = bias.w;
  }
  for (int k = 0; k < 128; k += 4){
    float4 w0 = *(const float4*)&w_lds[(k + 0) * 68 + tc * 4];
    float4 w1 = *(const float4*)&w_lds[(k + 1) * 68 + tc * 4];
    float4 w2 = *(const float4*)&w_lds[(k + 2) * 68 + tc * 4];
    float4 w3 = *(const float4*)&w_lds[(k + 3) * 68 + tc * 4];
#pragma unroll
    for (int r = 0; r < 4; ++r){
      float4 a = *(const float4*)&a_lds[(tr * 4 + r) * 132 + k];
      acc[r][0] += a.x * w0.x + a.y * w1.x + a.z * w2.x + a.w * w3.x;
      acc[r][1] += a.x * w0.y + a.y * w1.y + a.z * w2.y + a.w * w3.y;
      acc[r][2] += a.x * w0.z + a.y * w1.z + a.z * w2.z + a.w * w3.z;
      acc[r][3] += a.x * w0.w + a.y * w1.w + a.z * w2.w + a.w * w3.w;
    }
  }
#pragma unroll
  for (int r = 0; r < 4; ++r){
    int gr = row0 + tr * 4 + r;
    if (gr < N)
      *(float4*)&xout[gr * 64 + tc * 4] =
          make_float4(fmaxf(acc[r][0], 0.f), fmaxf(acc[r][1], 0.f),
                      fmaxf(acc[r][2], 0.f), fmaxf(acc[r][3], 0.f));
  }
}

extern "C" void kernel_launch(void* const* d_in, const int* in_sizes, int n_in,
                              void* d_out, int out_size, void* d_ws, size_t ws_size,
                              hipStream_t stream) {
  const float* x0    = (const float*)d_in[0];
  const int*   ei    = (const int*)d_in[1];
  const float* W1    = (const float*)d_in[2];
  const float* b1    = (const float*)d_in[3];
  const float* gamma = (const float*)d_in[4];
  const float* beta  = (const float*)d_in[5];
  const float* W2    = (const float*)d_in[6];
  const float* b2    = (const float*)d_in[7];
  const float* tptr  = (const float*)d_in[8];

  const int N = NN;
  const int E = in_sizes[1] / 2;
  const int* src = ei;
  const int* dst = ei + E;

  float* ws = (float*)d_ws;
  float* A  = ws;                 // N*64 : segmax (as uint) then h0
  float* B  = A + N * 64;         // N*64 : den
  float* C  = B + N * 64;         // N*64 : num
  float* bn = C + N * 64;         // 512  : sum | sumsq | scale | shift
  float* D  = bn + 512;           // N*128: h1
  float* out = (float*)d_out;

  const int zero_n4 = (N * 64 * 3 + 512) / 4;
  const int edge_blocks = (E * 64 + 255) / 256;
  const int row_blocks = (N + 63) / 64;

  for (int l = 0; l < 2; ++l){
    const float* xin = (l == 0) ? x0 : out;   // layer0 writes d_out, layer1 reads it
    zero_kernel<<<(zero_n4 + 255) / 256, 256, 0, stream>>>((float4*)A, zero_n4);
    seg_max_kernel<<<edge_blocks, 256, 0, stream>>>(xin, src, dst, tptr, l,
                                                    (unsigned*)A, E);
    seg_sum_kernel<<<edge_blocks, 256, 0, stream>>>(xin, src, dst, tptr, l,
                                                    (const unsigned*)A, B, C, E);
    combine_kernel<<<(N * 64 + 255) / 256, 256, 0, stream>>>(xin, B, C, A, N * 64);
    gemm1_kernel<<<row_blocks, 256, 0, stream>>>(A, W1 + l * 8192, b1 + l * 128, D, N);
    bn_stats_kernel<<<256, 128, 0, stream>>>(D, bn, N);
    bn_final_kernel<<<1, 128, 0, stream>>>(bn, gamma, beta, l, N);
    gemm2_kernel<<<row_blocks, 256, 0, stream>>>(D, bn, W2 + l * 8192, b2 + l * 64,
                                                 out, N);
  }
}

// Round 2
// 632.392 us; speedup vs baseline: 1.9736x; 1.9736x over previous
//
#include <hip/hip_runtime.h>
#include <math.h>

#define NN 50000
#define EPSM 1e-7f
#define BN_EPS 1e-5f

// ---------------- CSR build ----------------

__global__ __launch_bounds__(256) void hist_kernel(const int* __restrict__ dst,
                                                   int* __restrict__ deg, int E){
  int e = blockIdx.x * 256 + threadIdx.x;
  if (e < E) atomicAdd(&deg[dst[e]], 1);
}

// single-block exclusive scan over deg[0..NN) -> rowptr, cur
__global__ __launch_bounds__(1024) void scan_kernel(const int* __restrict__ deg,
                                                    int* __restrict__ rowptr,
                                                    int* __restrict__ cur){
  __shared__ int wtot[16];
  __shared__ int carry_s;
  int t = threadIdx.x, lane = t & 63, w = t >> 6;
  if (t == 0) carry_s = 0;
  __syncthreads();
  for (int base = 0; base < NN; base += 1024){
    int i = base + t;
    int v = (i < NN) ? deg[i] : 0;
    int sc = v;
#pragma unroll
    for (int off = 1; off < 64; off <<= 1){
      int n = __shfl_up(sc, off);
      if (lane >= off) sc += n;
    }
    if (lane == 63) wtot[w] = sc;
    __syncthreads();
    if (t == 0){
      int s = carry_s;
#pragma unroll
      for (int k = 0; k < 16; ++k){ int a = wtot[k]; wtot[k] = s; s += a; }
      carry_s = s;
    }
    __syncthreads();
    int exc = wtot[w] + sc - v;
    if (i < NN){ rowptr[i] = exc; cur[i] = exc; }
    __syncthreads();   // protect wtot/carry_s before next iteration
  }
  if (t == 0) rowptr[NN] = carry_s;
}

// scatter src ids into dst-sorted order
__global__ __launch_bounds__(256) void scatter_kernel(const int* __restrict__ src,
                                                      const int* __restrict__ dst,
                                                      int* __restrict__ cur,
                                                      int* __restrict__ srcs, int E){
  int e = blockIdx.x * 256 + threadIdx.x;
  if (e < E){
    int p = atomicAdd(&cur[dst[e]], 1);
    srcs[p] = src[e];
  }
}

// ---------------- softmax aggregation, one wave per node ----------------

__global__ __launch_bounds__(256) void aggregate_kernel(
    const float* __restrict__ x, const int* __restrict__ rowptr,
    const int* __restrict__ srcs, const float* __restrict__ tptr, int layer,
    float* __restrict__ h0){
  int node = blockIdx.x * 4 + (threadIdx.x >> 6);
  int c = threadIdx.x & 63;
  float t = tptr[layer];
  int beg = rowptr[node], end = rowptr[node + 1];
  float mx = -1e30f;
  for (int e = beg; e < end; ++e){
    int s = srcs[e];
    float m = fmaxf(x[s * 64 + c], 0.f) + EPSM;
    mx = fmaxf(mx, m * t);
  }
  float den = 0.f, num = 0.f;
  for (int e = beg; e < end; ++e){
    int s = srcs[e];
    float m = fmaxf(x[s * 64 + c], 0.f) + EPSM;
    float ex = __expf(m * t - mx);
    den += ex;
    num += m * ex;
  }
  h0[node * 64 + c] = num / (den + 1e-16f) + x[node * 64 + c];
}

// ---------------- MLP: gemm1 -> BN -> relu -> gemm2 -> relu ----------------

// h1[N,128] = h0[N,64] @ W1[64,128] + b1 ; 64-row x 128-col tile per block
__global__ __launch_bounds__(256) void gemm1_kernel(
    const float* __restrict__ h0, const float* __restrict__ W1,
    const float* __restrict__ b1, float* __restrict__ h1, int N){
  __shared__ float a_lds[64 * 68];
  __shared__ float w_lds[64 * 128];
  int t = threadIdx.x;
  const float4* wg = (const float4*)W1;
  float4* wl = (float4*)w_lds;
#pragma unroll
  for (int i = 0; i < 8; ++i) wl[t + 256 * i] = wg[t + 256 * i];
  int row0 = blockIdx.x * 64;
#pragma unroll
  for (int i = 0; i < 4; ++i){
    int li = t + 256 * i;
    int r = li >> 4, q = li & 15;
    int gr = row0 + r;
    float4 v = make_float4(0.f, 0.f, 0.f, 0.f);
    if (gr < N) v = ((const float4*)h0)[gr * 16 + q];
    *(float4*)&a_lds[r * 68 + q * 4] = v;
  }
  __syncthreads();
  int tc = t & 31, tr = t >> 5;
  float4 bias = ((const float4*)b1)[tc];
  float acc[8][4];
#pragma unroll
  for (int r = 0; r < 8; ++r){
    acc[r][0] = bias.x; acc[r][1] = bias.y; acc[r][2] = bias.z; acc[r][3] = bias.w;
  }
  for (int k = 0; k < 64; k += 4){
    float4 w0 = *(const float4*)&w_lds[(k + 0) * 128 + tc * 4];
    float4 w1 = *(const float4*)&w_lds[(k + 1) * 128 + tc * 4];
    float4 w2 = *(const float4*)&w_lds[(k + 2) * 128 + tc * 4];
    float4 w3 = *(const float4*)&w_lds[(k + 3) * 128 + tc * 4];
#pragma unroll
    for (int r = 0; r < 8; ++r){
      float4 a = *(const float4*)&a_lds[(tr * 8 + r) * 68 + k];
      acc[r][0] += a.x * w0.x + a.y * w1.x + a.z * w2.x + a.w * w3.x;
      acc[r][1] += a.x * w0.y + a.y * w1.y + a.z * w2.y + a.w * w3.y;
      acc[r][2] += a.x * w0.z + a.y * w1.z + a.z * w2.z + a.w * w3.z;
      acc[r][3] += a.x * w0.w + a.y * w1.w + a.z * w2.w + a.w * w3.w;
    }
  }
#pragma unroll
  for (int r = 0; r < 8; ++r){
    int gr = row0 + tr * 8 + r;
    if (gr < N)
      *(float4*)&h1[gr * 128 + tc * 4] =
          make_float4(acc[r][0], acc[r][1], acc[r][2], acc[r][3]);
  }
}

__global__ __launch_bounds__(128) void bn_stats_kernel(
    const float* __restrict__ h1, float* __restrict__ bn, int N){
  int c = threadIdx.x;
  float s = 0.f, s2 = 0.f;
  for (int r = blockIdx.x; r < N; r += gridDim.x){
    float v = h1[r * 128 + c];
    s += v; s2 += v * v;
  }
  atomicAdd(&bn[c], s);
  atomicAdd(&bn[128 + c], s2);
}

__global__ void bn_final_kernel(float* __restrict__ bn,
                                const float* __restrict__ gamma,
                                const float* __restrict__ beta, int layer, int N){
  int c = threadIdx.x;   // 128 threads
  float mean = bn[c] / (float)N;
  float var = bn[128 + c] / (float)N - mean * mean;
  var = fmaxf(var, 0.f);
  float sc = gamma[layer * 128 + c] / sqrtf(var + BN_EPS);
  bn[256 + c] = sc;
  bn[384 + c] = beta[layer * 128 + c] - mean * sc;
}

__global__ __launch_bounds__(256) void gemm2_kernel(
    const float* __restrict__ h1, const float* __restrict__ bn,
    const float* __restrict__ W2, const float* __restrict__ b2,
    float* __restrict__ xout, int N){
  __shared__ float a_lds[64 * 132];
  __shared__ float w_lds[128 * 68];
  int t = threadIdx.x;
  const float4* wg = (const float4*)W2;
#pragma unroll
  for (int i = 0; i < 8; ++i){
    int li = t + 256 * i;
    int k = li >> 4, q = li & 15;
    *(float4*)&w_lds[k * 68 + q * 4] = wg[li];
  }
  int row0 = blockIdx.x * 64;
  const float* scale = bn + 256;
  const float* shift = bn + 384;
#pragma unroll
  for (int i = 0; i < 8; ++i){
    int li = t + 256 * i;
    int r = li >> 5, q = li & 31;
    int gr = row0 + r;
    float4 v = make_float4(0.f, 0.f, 0.f, 0.f);
    if (gr < N) v = ((const float4*)h1)[gr * 32 + q];
    float4 sc = ((const float4*)scale)[q];
    float4 sh = ((const float4*)shift)[q];
    v.x = fmaxf(v.x * sc.x + sh.x, 0.f);
    v.y = fmaxf(v.y * sc.y + sh.y, 0.f);
    v.z = fmaxf(v.z * sc.z + sh.z, 0.f);
    v.w = fmaxf(v.w * sc.w + sh.w, 0.f);
    *(float4*)&a_lds[r * 132 + q * 4] = v;
  }
  __syncthreads();
  int tc = t & 15, tr = t >> 4;
  float4 bias = ((const float4*)b2)[tc];
  float acc[4][4];
#pragma unroll
  for (int r = 0; r < 4; ++r){
    acc[r][0] = bias.x; acc[r][1] = bias.y; acc[r][2] = bias.z; acc[r][3] = bias.w;
  }
  for (int k = 0; k < 128; k += 4){
    float4 w0 = *(const float4*)&w_lds[(k + 0) * 68 + tc * 4];
    float4 w1 = *(const float4*)&w_lds[(k + 1) * 68 + tc * 4];
    float4 w2 = *(const float4*)&w_lds[(k + 2) * 68 + tc * 4];
    float4 w3 = *(const float4*)&w_lds[(k + 3) * 68 + tc * 4];
#pragma unroll
    for (int r = 0; r < 4; ++r){
      float4 a = *(const float4*)&a_lds[(tr * 4 + r) * 132 + k];
      acc[r][0] += a.x * w0.x + a.y * w1.x + a.z * w2.x + a.w * w3.x;
      acc[r][1] += a.x * w0.y + a.y * w1.y + a.z * w2.y + a.w * w3.y;
      acc[r][2] += a.x * w0.z + a.y * w1.z + a.z * w2.z + a.w * w3.z;
      acc[r][3] += a.x * w0.w + a.y * w1.w + a.z * w2.w + a.w * w3.w;
    }
  }
#pragma unroll
  for (int r = 0; r < 4; ++r){
    int gr = row0 + tr * 4 + r;
    if (gr < N)
      *(float4*)&xout[gr * 64 + tc * 4] =
          make_float4(fmaxf(acc[r][0], 0.f), fmaxf(acc[r][1], 0.f),
                      fmaxf(acc[r][2], 0.f), fmaxf(acc[r][3], 0.f));
  }
}

extern "C" void kernel_launch(void* const* d_in, const int* in_sizes, int n_in,
                              void* d_out, int out_size, void* d_ws, size_t ws_size,
                              hipStream_t stream) {
  const float* x0    = (const float*)d_in[0];
  const int*   ei    = (const int*)d_in[1];
  const float* W1    = (const float*)d_in[2];
  const float* b1    = (const float*)d_in[3];
  const float* gamma = (const float*)d_in[4];
  const float* beta  = (const float*)d_in[5];
  const float* W2    = (const float*)d_in[6];
  const float* b2    = (const float*)d_in[7];
  const float* tptr  = (const float*)d_in[8];

  const int N = NN;
  const int E = in_sizes[1] / 2;
  const int* src = ei;
  const int* dst = ei + E;

  float* ws  = (float*)d_ws;
  float* h0  = ws;                    // N*64
  float* h1  = h0 + N * 64;           // N*128
  float* bn  = h1 + N * 128;          // 512
  int* rowptr = (int*)(bn + 512);     // N+1
  int* cur    = rowptr + N + 2;       // N   (deg, then cursor)
  int* srcs   = cur + N;              // E

  float* out = (float*)d_out;

  const int row_blocks = (N + 63) / 64;
  const int edge_blocks = (E + 255) / 256;

  // ---- CSR build (edge structure is layer-invariant) ----
  hipMemsetAsync(cur, 0, N * sizeof(int), stream);
  hist_kernel<<<edge_blocks, 256, 0, stream>>>(dst, cur, E);
  scan_kernel<<<1, 1024, 0, stream>>>(cur, rowptr, cur);
  scatter_kernel<<<edge_blocks, 256, 0, stream>>>(src, dst, cur, srcs, E);

  for (int l = 0; l < 2; ++l){
    const float* xin = (l == 0) ? x0 : out;   // layer0 writes d_out, layer1 reads it
    aggregate_kernel<<<(N + 3) / 4, 256, 0, stream>>>(xin, rowptr, srcs, tptr, l, h0);
    gemm1_kernel<<<row_blocks, 256, 0, stream>>>(h0, W1 + l * 8192, b1 + l * 128, h1, N);
    hipMemsetAsync(bn, 0, 256 * sizeof(float), stream);
    bn_stats_kernel<<<256, 128, 0, stream>>>(h1, bn, N);
    bn_final_kernel<<<1, 128, 0, stream>>>(bn, gamma, beta, l, N);
    gemm2_kernel<<<row_blocks, 256, 0, stream>>>(h1, bn, W2 + l * 8192, b2 + l * 64,
                                                 out, N);
  }
}

// Round 3
// 549.226 us; speedup vs baseline: 2.2725x; 1.1514x over previous
//
#include <hip/hip_runtime.h>
#include <math.h>

#define NN 50000
#define EPSM 1e-7f
#define BN_EPS 1e-5f

// ---------------- CSR build ----------------

__global__ __launch_bounds__(256) void hist_kernel(const int* __restrict__ dst,
                                                   int* __restrict__ deg, int E){
  int e = blockIdx.x * 256 + threadIdx.x;
  if (e < E) atomicAdd(&deg[dst[e]], 1);
}

// chunked single-block exclusive scan: deg (in `cur`) -> rowptr, cur
__global__ __launch_bounds__(1024) void scan_kernel(int* __restrict__ cur,
                                                    int* __restrict__ rowptr){
  __shared__ int wt[16];
  int t = threadIdx.x, lane = t & 63, w = t >> 6;
  const int CH = (NN + 1023) / 1024;           // 49
  int b = t * CH;
  int e = b + CH < NN ? b + CH : NN;
  int s = 0;
  for (int i = b; i < e; ++i) s += cur[i];
  int sc = s;
#pragma unroll
  for (int off = 1; off < 64; off <<= 1){
    int n = __shfl_up(sc, off);
    if (lane >= off) sc += n;
  }
  if (lane == 63) wt[w] = sc;
  __syncthreads();
  if (t == 0){
    int a = 0;
#pragma unroll
    for (int k = 0; k < 16; ++k){ int v = wt[k]; wt[k] = a; a += v; }
    rowptr[NN] = a;
  }
  __syncthreads();
  int run = wt[w] + sc - s;                    // exclusive prefix of this chunk
  for (int i = b; i < e; ++i){
    int d = cur[i];
    rowptr[i] = run;
    cur[i] = run;
    run += d;
  }
}

// scatter src ids into dst-sorted order
__global__ __launch_bounds__(256) void scatter_kernel(const int* __restrict__ src,
                                                      const int* __restrict__ dst,
                                                      int* __restrict__ cur,
                                                      int* __restrict__ srcs, int E){
  int e = blockIdx.x * 256 + threadIdx.x;
  if (e < E){
    int p = atomicAdd(&cur[dst[e]], 1);
    srcs[p] = src[e];
  }
}

// ---------------- per-layer init: colmin/colmax seeds + bn sums ----------------

__global__ void init_kernel(unsigned* __restrict__ mm, float* __restrict__ bn){
  int t = threadIdx.x;          // 256 threads
  if (t < 64) mm[t] = 0x7F7FFFFFu;      // colmin seed = FLT_MAX
  else if (t < 128) mm[t] = 0u;         // colmax seed = 0
  bn[t] = 0.f;                          // sum / sumsq accumulators
}

// column min/max of m = relu(x)+eps  (positive floats: uint compare == float compare)
__global__ __launch_bounds__(256) void colminmax_kernel(
    const float* __restrict__ x, unsigned* __restrict__ mm, int N){
  int c = threadIdx.x & 63;
  int r0 = blockIdx.x * 4 + (threadIdx.x >> 6);
  float mx = 0.f, mn = 1e30f;
  for (int r = r0; r < N; r += gridDim.x * 4){
    float m = fmaxf(x[r * 64 + c], 0.f) + EPSM;
    mx = fmaxf(mx, m);
    mn = fminf(mn, m);
  }
  atomicMin(&mm[c], __float_as_uint(mn));
  atomicMax(&mm[64 + c], __float_as_uint(mx));
}

// ---------------- single-pass softmax aggregation, one wave per node ----------------
// exp(lg - B) with fixed per-channel B >= all logits: num/den ratio is exact.

__global__ __launch_bounds__(256) void aggregate_kernel(
    const float* __restrict__ x, const int* __restrict__ rowptr,
    const int* __restrict__ srcs, const float* __restrict__ tptr, int layer,
    const unsigned* __restrict__ mm, float* __restrict__ h0, int N){
  int node = blockIdx.x * 4 + (threadIdx.x >> 6);
  if (node >= N) return;
  int c = threadIdx.x & 63;
  float t = tptr[layer];
  float mn = __uint_as_float(mm[c]);
  float mx = __uint_as_float(mm[64 + c]);
  float B = fmaxf(t * mx, t * mn);      // upper bound on logits (any sign of t)
  int beg = rowptr[node], end = rowptr[node + 1];
  float den0 = 0.f, den1 = 0.f, den2 = 0.f, den3 = 0.f;
  float num0 = 0.f, num1 = 0.f, num2 = 0.f, num3 = 0.f;
  int e = beg;
  for (; e + 4 <= end; e += 4){
    int s0 = srcs[e], s1 = srcs[e + 1], s2 = srcs[e + 2], s3 = srcs[e + 3];
    float v0 = x[s0 * 64 + c], v1 = x[s1 * 64 + c];
    float v2 = x[s2 * 64 + c], v3 = x[s3 * 64 + c];
    float m0 = fmaxf(v0, 0.f) + EPSM, m1 = fmaxf(v1, 0.f) + EPSM;
    float m2 = fmaxf(v2, 0.f) + EPSM, m3 = fmaxf(v3, 0.f) + EPSM;
    float e0 = __expf(m0 * t - B), e1 = __expf(m1 * t - B);
    float e2 = __expf(m2 * t - B), e3 = __expf(m3 * t - B);
    den0 += e0; num0 += m0 * e0;
    den1 += e1; num1 += m1 * e1;
    den2 += e2; num2 += m2 * e2;
    den3 += e3; num3 += m3 * e3;
  }
  for (; e < end; ++e){
    int s = srcs[e];
    float m = fmaxf(x[s * 64 + c], 0.f) + EPSM;
    float ex = __expf(m * t - B);
    den0 += ex; num0 += m * ex;
  }
  float den = (den0 + den1) + (den2 + den3);
  float num = (num0 + num1) + (num2 + num3);
  h0[node * 64 + c] = num / (den + 1e-16f) + x[node * 64 + c];
}

// ---------------- MLP ----------------

// h1[N,128] = h0[N,64] @ W1[64,128] + b1 ; fused BN sum/sumsq accumulation
__global__ __launch_bounds__(256) void gemm1_kernel(
    const float* __restrict__ h0, const float* __restrict__ W1,
    const float* __restrict__ b1, float* __restrict__ h1,
    float* __restrict__ bn, int N){
  __shared__ float a_lds[64 * 68];
  __shared__ float w_lds[64 * 128];
  int t = threadIdx.x;
  const float4* wg = (const float4*)W1;
  float4* wl = (float4*)w_lds;
#pragma unroll
  for (int i = 0; i < 8; ++i) wl[t + 256 * i] = wg[t + 256 * i];
  int row0 = blockIdx.x * 64;
#pragma unroll
  for (int i = 0; i < 4; ++i){
    int li = t + 256 * i;
    int r = li >> 4, q = li & 15;
    int gr = row0 + r;
    float4 v = make_float4(0.f, 0.f, 0.f, 0.f);
    if (gr < N) v = ((const float4*)h0)[gr * 16 + q];
    *(float4*)&a_lds[r * 68 + q * 4] = v;
  }
  __syncthreads();
  int tc = t & 31, tr = t >> 5;
  float4 bias = ((const float4*)b1)[tc];
  float acc[8][4];
#pragma unroll
  for (int r = 0; r < 8; ++r){
    acc[r][0] = bias.x; acc[r][1] = bias.y; acc[r][2] = bias.z; acc[r][3] = bias.w;
  }
  for (int k = 0; k < 64; k += 4){
    float4 w0 = *(const float4*)&w_lds[(k + 0) * 128 + tc * 4];
    float4 w1 = *(const float4*)&w_lds[(k + 1) * 128 + tc * 4];
    float4 w2 = *(const float4*)&w_lds[(k + 2) * 128 + tc * 4];
    float4 w3 = *(const float4*)&w_lds[(k + 3) * 128 + tc * 4];
#pragma unroll
    for (int r = 0; r < 8; ++r){
      float4 a = *(const float4*)&a_lds[(tr * 8 + r) * 68 + k];
      acc[r][0] += a.x * w0.x + a.y * w1.x + a.z * w2.x + a.w * w3.x;
      acc[r][1] += a.x * w0.y + a.y * w1.y + a.z * w2.y + a.w * w3.y;
      acc[r][2] += a.x * w0.z + a.y * w1.z + a.z * w2.z + a.w * w3.z;
      acc[r][3] += a.x * w0.w + a.y * w1.w + a.z * w2.w + a.w * w3.w;
    }
  }
  float s[4] = {0.f, 0.f, 0.f, 0.f}, s2[4] = {0.f, 0.f, 0.f, 0.f};
#pragma unroll
  for (int r = 0; r < 8; ++r){
    int gr = row0 + tr * 8 + r;
    if (gr < N){
      *(float4*)&h1[gr * 128 + tc * 4] =
          make_float4(acc[r][0], acc[r][1], acc[r][2], acc[r][3]);
#pragma unroll
      for (int j = 0; j < 4; ++j){ s[j] += acc[r][j]; s2[j] += acc[r][j] * acc[r][j]; }
    }
  }
  // block-level BN-stat reduction in LDS (reuse a_lds), then 256 global atomics
  __syncthreads();
  float* red = a_lds;
  if (t < 256){ red[t] = 0.f; }
  __syncthreads();
#pragma unroll
  for (int j = 0; j < 4; ++j){
    atomicAdd(&red[tc * 4 + j], s[j]);
    atomicAdd(&red[128 + tc * 4 + j], s2[j]);
  }
  __syncthreads();
  if (t < 256) atomicAdd(&bn[t], red[t]);
}

// xout = relu( relu(BN(h1)) @ W2 + b2 ) ; BN finalize + apply fused in preamble
__global__ __launch_bounds__(256) void gemm2_kernel(
    const float* __restrict__ h1, const float* __restrict__ bn,
    const float* __restrict__ gamma, const float* __restrict__ beta, int layer,
    const float* __restrict__ W2, const float* __restrict__ b2,
    float* __restrict__ xout, int N){
  __shared__ float a_lds[64 * 132];
  __shared__ float w_lds[128 * 68];
  __shared__ float ss[256];     // scale[128], shift[128]
  int t = threadIdx.x;
  if (t < 128){
    float mean = bn[t] * (1.f / (float)N);
    float var = bn[128 + t] * (1.f / (float)N) - mean * mean;
    var = fmaxf(var, 0.f);
    float sc = gamma[layer * 128 + t] / sqrtf(var + BN_EPS);
    ss[t] = sc;
    ss[128 + t] = beta[layer * 128 + t] - mean * sc;
  }
  const float4* wg = (const float4*)W2;
#pragma unroll
  for (int i = 0; i < 8; ++i){
    int li = t + 256 * i;
    int k = li >> 4, q = li & 15;
    *(float4*)&w_lds[k * 68 + q * 4] = wg[li];
  }
  __syncthreads();              // ss ready before staging uses it
  int row0 = blockIdx.x * 64;
#pragma unroll
  for (int i = 0; i < 8; ++i){
    int li = t + 256 * i;
    int r = li >> 5, q = li & 31;
    int gr = row0 + r;
    float4 v = make_float4(0.f, 0.f, 0.f, 0.f);
    if (gr < N) v = ((const float4*)h1)[gr * 32 + q];
    float4 sc = *(const float4*)&ss[q * 4];
    float4 sh = *(const float4*)&ss[128 + q * 4];
    v.x = fmaxf(v.x * sc.x + sh.x, 0.f);
    v.y = fmaxf(v.y * sc.y + sh.y, 0.f);
    v.z = fmaxf(v.z * sc.z + sh.z, 0.f);
    v.w = fmaxf(v.w * sc.w + sh.w, 0.f);
    *(float4*)&a_lds[r * 132 + q * 4] = v;
  }
  __syncthreads();
  int tc = t & 15, tr = t >> 4;
  float4 bias = ((const float4*)b2)[tc];
  float acc[4][4];
#pragma unroll
  for (int r = 0; r < 4; ++r){
    acc[r][0] = bias.x; acc[r][1] = bias.y; acc[r][2] = bias.z; acc[r][3] = bias.w;
  }
  for (int k = 0; k < 128; k += 4){
    float4 w0 = *(const float4*)&w_lds[(k + 0) * 68 + tc * 4];
    float4 w1 = *(const float4*)&w_lds[(k + 1) * 68 + tc * 4];
    float4 w2 = *(const float4*)&w_lds[(k + 2) * 68 + tc * 4];
    float4 w3 = *(const float4*)&w_lds[(k + 3) * 68 + tc * 4];
#pragma unroll
    for (int r = 0; r < 4; ++r){
      float4 a = *(const float4*)&a_lds[(tr * 4 + r) * 132 + k];
      acc[r][0] += a.x * w0.x + a.y * w1.x + a.z * w2.x + a.w * w3.x;
      acc[r][1] += a.x * w0.y + a.y * w1.y + a.z * w2.y + a.w * w3.y;
      acc[r][2] += a.x * w0.z + a.y * w1.z + a.z * w2.z + a.w * w3.z;
      acc[r][3] += a.x * w0.w + a.y * w1.w + a.z * w2.w + a.w * w3.w;
    }
  }
#pragma unroll
  for (int r = 0; r < 4; ++r){
    int gr = row0 + tr * 4 + r;
    if (gr < N)
      *(float4*)&xout[gr * 64 + tc * 4] =
          make_float4(fmaxf(acc[r][0], 0.f), fmaxf(acc[r][1], 0.f),
                      fmaxf(acc[r][2], 0.f), fmaxf(acc[r][3], 0.f));
  }
}

extern "C" void kernel_launch(void* const* d_in, const int* in_sizes, int n_in,
                              void* d_out, int out_size, void* d_ws, size_t ws_size,
                              hipStream_t stream) {
  const float* x0    = (const float*)d_in[0];
  const int*   ei    = (const int*)d_in[1];
  const float* W1    = (const float*)d_in[2];
  const float* b1    = (const float*)d_in[3];
  const float* gamma = (const float*)d_in[4];
  const float* beta  = (const float*)d_in[5];
  const float* W2    = (const float*)d_in[6];
  const float* b2    = (const float*)d_in[7];
  const float* tptr  = (const float*)d_in[8];

  const int N = NN;
  const int E = in_sizes[1] / 2;
  const int* src = ei;
  const int* dst = ei + E;

  float* ws  = (float*)d_ws;
  float* h0  = ws;                    // N*64
  float* h1  = h0 + N * 64;           // N*128
  float* bn  = h1 + N * 128;          // 256: sum|sumsq
  unsigned* mm = (unsigned*)(bn + 256);  // 128: colmin|colmax
  int* rowptr = (int*)(mm + 128);     // N+1
  int* cur    = rowptr + N + 2;       // N   (deg, then cursor)
  int* srcs   = cur + N;              // E

  float* out = (float*)d_out;

  const int row_blocks = (N + 63) / 64;
  const int edge_blocks = (E + 255) / 256;

  // ---- CSR build (edge structure is layer-invariant) ----
  hipMemsetAsync(cur, 0, N * sizeof(int), stream);
  hist_kernel<<<edge_blocks, 256, 0, stream>>>(dst, cur, E);
  scan_kernel<<<1, 1024, 0, stream>>>(cur, rowptr);
  scatter_kernel<<<edge_blocks, 256, 0, stream>>>(src, dst, cur, srcs, E);

  for (int l = 0; l < 2; ++l){
    const float* xin = (l == 0) ? x0 : out;   // layer0 writes d_out, layer1 reads it
    init_kernel<<<1, 256, 0, stream>>>(mm, bn);
    colminmax_kernel<<<128, 256, 0, stream>>>(xin, mm, N);
    aggregate_kernel<<<(N + 3) / 4, 256, 0, stream>>>(xin, rowptr, srcs, tptr, l,
                                                      mm, h0, N);
    gemm1_kernel<<<row_blocks, 256, 0, stream>>>(h0, W1 + l * 8192, b1 + l * 128,
                                                 h1, bn, N);
    gemm2_kernel<<<row_blocks, 256, 0, stream>>>(h1, bn, gamma, beta, l,
                                                 W2 + l * 8192, b2 + l * 64, out, N);
  }
}

// Round 4
// 458.900 us; speedup vs baseline: 2.7197x; 1.1968x over previous
//
#include <hip/hip_runtime.h>
#include <math.h>

#define NN 50000
#define EPSM 1e-7f
#define BN_EPS 1e-5f

// ---------------- CSR build (segments in arbitrary node order) ----------------

__global__ __launch_bounds__(256) void hist_kernel(const int* __restrict__ dst,
                                                   int* __restrict__ deg, int E){
  int e = blockIdx.x * 256 + threadIdx.x;
  if (e < E) atomicAdd(&deg[dst[e]], 1);
}

// assign each node a contiguous segment [start, start+deg) via per-wave
// shuffle-scan + one atomicAdd per wave on a global cursor. Segment order
// across nodes is arbitrary — aggregation only needs per-node contiguity.
__global__ __launch_bounds__(256) void assign_kernel(const int* __restrict__ deg,
                                                     int* __restrict__ start,
                                                     int* __restrict__ cur,
                                                     int* __restrict__ total, int N){
  int i = blockIdx.x * 256 + threadIdx.x;
  int lane = threadIdx.x & 63;
  int d = (i < N) ? deg[i] : 0;
  int sc = d;
#pragma unroll
  for (int off = 1; off < 64; off <<= 1){
    int n = __shfl_up(sc, off);
    if (lane >= off) sc += n;
  }
  int wtot = __shfl(sc, 63);
  int base = 0;
  if (lane == 63) base = atomicAdd(total, wtot);
  base = __shfl(base, 63);
  int exc = base + sc - d;
  if (i < N){ start[i] = exc; cur[i] = exc; }
}

// scatter src ids into segment order; afterwards cur[node] == segment end
__global__ __launch_bounds__(256) void scatter_kernel(const int* __restrict__ src,
                                                      const int* __restrict__ dst,
                                                      int* __restrict__ cur,
                                                      int* __restrict__ srcs, int E){
  int e = blockIdx.x * 256 + threadIdx.x;
  if (e < E){
    int p = atomicAdd(&cur[dst[e]], 1);
    srcs[p] = src[e];
  }
}

// ---------------- per-layer init: colmin/colmax seeds + bn sums ----------------

__global__ void init_kernel(unsigned* __restrict__ mm, float* __restrict__ bn){
  int t = threadIdx.x;          // 256 threads
  if (t < 64) mm[t] = 0x7F7FFFFFu;      // colmin seed = FLT_MAX
  else if (t < 128) mm[t] = 0u;         // colmax seed = 0
  bn[t] = 0.f;                          // sum / sumsq accumulators
}

// column min/max of m = relu(x)+eps  (positive floats: uint compare == float compare)
__global__ __launch_bounds__(256) void colminmax_kernel(
    const float* __restrict__ x, unsigned* __restrict__ mm, int N){
  int c = threadIdx.x & 63;
  int r0 = blockIdx.x * 4 + (threadIdx.x >> 6);
  float mx = 0.f, mn = 1e30f;
  for (int r = r0; r < N; r += gridDim.x * 4){
    float m = fmaxf(x[r * 64 + c], 0.f) + EPSM;
    mx = fmaxf(mx, m);
    mn = fminf(mn, m);
  }
  atomicMin(&mm[c], __float_as_uint(mn));
  atomicMax(&mm[64 + c], __float_as_uint(mx));
}

// ---------------- single-pass softmax aggregation, one wave per node ----------------
// exp(lg - B) with fixed per-channel B >= all logits: num/den ratio is exact.

__global__ __launch_bounds__(256) void aggregate_kernel(
    const float* __restrict__ x, const int* __restrict__ start,
    const int* __restrict__ segend, const int* __restrict__ srcs,
    const float* __restrict__ tptr, int layer,
    const unsigned* __restrict__ mm, float* __restrict__ h0, int N){
  int node = blockIdx.x * 4 + (threadIdx.x >> 6);
  if (node >= N) return;
  int c = threadIdx.x & 63;
  float t = tptr[layer];
  float mn = __uint_as_float(mm[c]);
  float mx = __uint_as_float(mm[64 + c]);
  float B = fmaxf(t * mx, t * mn);      // upper bound on logits (any sign of t)
  int beg = start[node], end = segend[node];
  float den0 = 0.f, den1 = 0.f, den2 = 0.f, den3 = 0.f;
  float num0 = 0.f, num1 = 0.f, num2 = 0.f, num3 = 0.f;
  int e = beg;
  for (; e + 4 <= end; e += 4){
    int s0 = srcs[e], s1 = srcs[e + 1], s2 = srcs[e + 2], s3 = srcs[e + 3];
    float v0 = x[s0 * 64 + c], v1 = x[s1 * 64 + c];
    float v2 = x[s2 * 64 + c], v3 = x[s3 * 64 + c];
    float m0 = fmaxf(v0, 0.f) + EPSM, m1 = fmaxf(v1, 0.f) + EPSM;
    float m2 = fmaxf(v2, 0.f) + EPSM, m3 = fmaxf(v3, 0.f) + EPSM;
    float e0 = __expf(m0 * t - B), e1 = __expf(m1 * t - B);
    float e2 = __expf(m2 * t - B), e3 = __expf(m3 * t - B);
    den0 += e0; num0 += m0 * e0;
    den1 += e1; num1 += m1 * e1;
    den2 += e2; num2 += m2 * e2;
    den3 += e3; num3 += m3 * e3;
  }
  for (; e < end; ++e){
    int s = srcs[e];
    float m = fmaxf(x[s * 64 + c], 0.f) + EPSM;
    float ex = __expf(m * t - B);
    den0 += ex; num0 += m * ex;
  }
  float den = (den0 + den1) + (den2 + den3);
  float num = (num0 + num1) + (num2 + num3);
  h0[node * 64 + c] = num / (den + 1e-16f) + x[node * 64 + c];
}

// ---------------- MLP ----------------

// h1[N,128] = h0[N,64] @ W1[64,128] + b1 ; fused BN sum/sumsq accumulation
__global__ __launch_bounds__(256) void gemm1_kernel(
    const float* __restrict__ h0, const float* __restrict__ W1,
    const float* __restrict__ b1, float* __restrict__ h1,
    float* __restrict__ bn, int N){
  __shared__ float a_lds[64 * 68];
  __shared__ float w_lds[64 * 128];
  int t = threadIdx.x;
  const float4* wg = (const float4*)W1;
  float4* wl = (float4*)w_lds;
#pragma unroll
  for (int i = 0; i < 8; ++i) wl[t + 256 * i] = wg[t + 256 * i];
  int row0 = blockIdx.x * 64;
#pragma unroll
  for (int i = 0; i < 4; ++i){
    int li = t + 256 * i;
    int r = li >> 4, q = li & 15;
    int gr = row0 + r;
    float4 v = make_float4(0.f, 0.f, 0.f, 0.f);
    if (gr < N) v = ((const float4*)h0)[gr * 16 + q];
    *(float4*)&a_lds[r * 68 + q * 4] = v;
  }
  __syncthreads();
  int tc = t & 31, tr = t >> 5;
  float4 bias = ((const float4*)b1)[tc];
  float acc[8][4];
#pragma unroll
  for (int r = 0; r < 8; ++r){
    acc[r][0] = bias.x; acc[r][1] = bias.y; acc[r][2] = bias.z; acc[r][3] = bias.w;
  }
  for (int k = 0; k < 64; k += 4){
    float4 w0 = *(const float4*)&w_lds[(k + 0) * 128 + tc * 4];
    float4 w1 = *(const float4*)&w_lds[(k + 1) * 128 + tc * 4];
    float4 w2 = *(const float4*)&w_lds[(k + 2) * 128 + tc * 4];
    float4 w3 = *(const float4*)&w_lds[(k + 3) * 128 + tc * 4];
#pragma unroll
    for (int r = 0; r < 8; ++r){
      float4 a = *(const float4*)&a_lds[(tr * 8 + r) * 68 + k];
      acc[r][0] += a.x * w0.x + a.y * w1.x + a.z * w2.x + a.w * w3.x;
      acc[r][1] += a.x * w0.y + a.y * w1.y + a.z * w2.y + a.w * w3.y;
      acc[r][2] += a.x * w0.z + a.y * w1.z + a.z * w2.z + a.w * w3.z;
      acc[r][3] += a.x * w0.w + a.y * w1.w + a.z * w2.w + a.w * w3.w;
    }
  }
  float s[4] = {0.f, 0.f, 0.f, 0.f}, s2[4] = {0.f, 0.f, 0.f, 0.f};
#pragma unroll
  for (int r = 0; r < 8; ++r){
    int gr = row0 + tr * 8 + r;
    if (gr < N){
      *(float4*)&h1[gr * 128 + tc * 4] =
          make_float4(acc[r][0], acc[r][1], acc[r][2], acc[r][3]);
#pragma unroll
      for (int j = 0; j < 4; ++j){ s[j] += acc[r][j]; s2[j] += acc[r][j] * acc[r][j]; }
    }
  }
  __syncthreads();
  float* red = a_lds;
  if (t < 256){ red[t] = 0.f; }
  __syncthreads();
#pragma unroll
  for (int j = 0; j < 4; ++j){
    atomicAdd(&red[tc * 4 + j], s[j]);
    atomicAdd(&red[128 + tc * 4 + j], s2[j]);
  }
  __syncthreads();
  if (t < 256) atomicAdd(&bn[t], red[t]);
}

// xout = relu( relu(BN(h1)) @ W2 + b2 ) ; BN finalize + apply fused in preamble
__global__ __launch_bounds__(256) void gemm2_kernel(
    const float* __restrict__ h1, const float* __restrict__ bn,
    const float* __restrict__ gamma, const float* __restrict__ beta, int layer,
    const float* __restrict__ W2, const float* __restrict__ b2,
    float* __restrict__ xout, int N){
  __shared__ float a_lds[64 * 132];
  __shared__ float w_lds[128 * 68];
  __shared__ float ss[256];     // scale[128], shift[128]
  int t = threadIdx.x;
  if (t < 128){
    float mean = bn[t] * (1.f / (float)N);
    float var = bn[128 + t] * (1.f / (float)N) - mean * mean;
    var = fmaxf(var, 0.f);
    float sc = gamma[layer * 128 + t] / sqrtf(var + BN_EPS);
    ss[t] = sc;
    ss[128 + t] = beta[layer * 128 + t] - mean * sc;
  }
  const float4* wg = (const float4*)W2;
#pragma unroll
  for (int i = 0; i < 8; ++i){
    int li = t + 256 * i;
    int k = li >> 4, q = li & 15;
    *(float4*)&w_lds[k * 68 + q * 4] = wg[li];
  }
  __syncthreads();
  int row0 = blockIdx.x * 64;
#pragma unroll
  for (int i = 0; i < 8; ++i){
    int li = t + 256 * i;
    int r = li >> 5, q = li & 31;
    int gr = row0 + r;
    float4 v = make_float4(0.f, 0.f, 0.f, 0.f);
    if (gr < N) v = ((const float4*)h1)[gr * 32 + q];
    float4 sc = *(const float4*)&ss[q * 4];
    float4 sh = *(const float4*)&ss[128 + q * 4];
    v.x = fmaxf(v.x * sc.x + sh.x, 0.f);
    v.y = fmaxf(v.y * sc.y + sh.y, 0.f);
    v.z = fmaxf(v.z * sc.z + sh.z, 0.f);
    v.w = fmaxf(v.w * sc.w + sh.w, 0.f);
    *(float4*)&a_lds[r * 132 + q * 4] = v;
  }
  __syncthreads();
  int tc = t & 15, tr = t >> 4;
  float4 bias = ((const float4*)b2)[tc];
  float acc[4][4];
#pragma unroll
  for (int r = 0; r < 4; ++r){
    acc[r][0] = bias.x; acc[r][1] = bias.y; acc[r][2] = bias.z; acc[r][3] = bias.w;
  }
  for (int k = 0; k < 128; k += 4){
    float4 w0 = *(const float4*)&w_lds[(k + 0) * 68 + tc * 4];
    float4 w1 = *(const float4*)&w_lds[(k + 1) * 68 + tc * 4];
    float4 w2 = *(const float4*)&w_lds[(k + 2) * 68 + tc * 4];
    float4 w3 = *(const float4*)&w_lds[(k + 3) * 68 + tc * 4];
#pragma unroll
    for (int r = 0; r < 4; ++r){
      float4 a = *(const float4*)&a_lds[(tr * 4 + r) * 132 + k];
      acc[r][0] += a.x * w0.x + a.y * w1.x + a.z * w2.x + a.w * w3.x;
      acc[r][1] += a.x * w0.y + a.y * w1.y + a.z * w2.y + a.w * w3.y;
      acc[r][2] += a.x * w0.z + a.y * w1.z + a.z * w2.z + a.w * w3.z;
      acc[r][3] += a.x * w0.w + a.y * w1.w + a.z * w2.w + a.w * w3.w;
    }
  }
#pragma unroll
  for (int r = 0; r < 4; ++r){
    int gr = row0 + tr * 4 + r;
    if (gr < N)
      *(float4*)&xout[gr * 64 + tc * 4] =
          make_float4(fmaxf(acc[r][0], 0.f), fmaxf(acc[r][1], 0.f),
                      fmaxf(acc[r][2], 0.f), fmaxf(acc[r][3], 0.f));
  }
}

extern "C" void kernel_launch(void* const* d_in, const int* in_sizes, int n_in,
                              void* d_out, int out_size, void* d_ws, size_t ws_size,
                              hipStream_t stream) {
  const float* x0    = (const float*)d_in[0];
  const int*   ei    = (const int*)d_in[1];
  const float* W1    = (const float*)d_in[2];
  const float* b1    = (const float*)d_in[3];
  const float* gamma = (const float*)d_in[4];
  const float* beta  = (const float*)d_in[5];
  const float* W2    = (const float*)d_in[6];
  const float* b2    = (const float*)d_in[7];
  const float* tptr  = (const float*)d_in[8];

  const int N = NN;
  const int E = in_sizes[1] / 2;
  const int* src = ei;
  const int* dst = ei + E;

  float* ws  = (float*)d_ws;
  float* h0  = ws;                       // N*64
  float* h1  = h0 + N * 64;              // N*128
  float* bn  = h1 + N * 128;             // 256: sum|sumsq
  unsigned* mm = (unsigned*)(bn + 256);  // 128: colmin|colmax
  int* deg   = (int*)(mm + 128);         // N
  int* total = deg + N;                  // 1
  int* start = total + 1;                // N
  int* cur   = start + N;                // N (becomes segment end after scatter)
  int* srcs  = cur + N;                  // E

  float* out = (float*)d_out;

  const int row_blocks = (N + 63) / 64;
  const int edge_blocks = (E + 255) / 256;
  const int node_blocks = (N + 255) / 256;

  // ---- CSR build (edge structure is layer-invariant) ----
  hipMemsetAsync(deg, 0, (N + 1) * sizeof(int), stream);   // deg + total
  hist_kernel<<<edge_blocks, 256, 0, stream>>>(dst, deg, E);
  assign_kernel<<<node_blocks, 256, 0, stream>>>(deg, start, cur, total, N);
  scatter_kernel<<<edge_blocks, 256, 0, stream>>>(src, dst, cur, srcs, E);

  for (int l = 0; l < 2; ++l){
    const float* xin = (l == 0) ? x0 : out;   // layer0 writes d_out, layer1 reads it
    init_kernel<<<1, 256, 0, stream>>>(mm, bn);
    colminmax_kernel<<<128, 256, 0, stream>>>(xin, mm, N);
    aggregate_kernel<<<(N + 3) / 4, 256, 0, stream>>>(xin, start, cur, srcs, tptr, l,
                                                      mm, h0, N);
    gemm1_kernel<<<row_blocks, 256, 0, stream>>>(h0, W1 + l * 8192, b1 + l * 128,
                                                 h1, bn, N);
    gemm2_kernel<<<row_blocks, 256, 0, stream>>>(h1, bn, gamma, beta, l,
                                                 W2 + l * 8192, b2 + l * 64, out, N);
  }
}

// Round 5
// 416.700 us; speedup vs baseline: 2.9952x; 1.1013x over previous
//
#include <hip/hip_runtime.h>
#include <math.h>

#define NN 50000
#define EPSM 1e-7f
#define BN_EPS 1e-5f

// ---------------- CSR build (segments in arbitrary node order) ----------------

// histogram of dst degrees; block 0 also seeds layer-0 colmin/colmax + bn sums
__global__ __launch_bounds__(256) void hist_kernel(const int* __restrict__ dst,
                                                   int* __restrict__ deg, int E,
                                                   unsigned* __restrict__ mm0,
                                                   float* __restrict__ bn0){
  if (blockIdx.x == 0){
    int t = threadIdx.x;
    if (t < 64) mm0[t] = 0x7F7FFFFFu;        // colmin seed = FLT_MAX
    else if (t < 128) mm0[t] = 0u;           // colmax seed = 0
    bn0[t] = 0.f;                            // bn sum/sumsq accumulators
  }
  int e = blockIdx.x * 256 + threadIdx.x;
  if (e < E) atomicAdd(&deg[dst[e]], 1);
}

// assign each node a contiguous segment [start, start+deg) via per-wave
// shuffle-scan + one atomicAdd per wave on a global cursor.
__global__ __launch_bounds__(256) void assign_kernel(const int* __restrict__ deg,
                                                     int* __restrict__ start,
                                                     int* __restrict__ cur,
                                                     int* __restrict__ total, int N){
  int i = blockIdx.x * 256 + threadIdx.x;
  int lane = threadIdx.x & 63;
  int d = (i < N) ? deg[i] : 0;
  int sc = d;
#pragma unroll
  for (int off = 1; off < 64; off <<= 1){
    int n = __shfl_up(sc, off);
    if (lane >= off) sc += n;
  }
  int wtot = __shfl(sc, 63);
  int base = 0;
  if (lane == 63) base = atomicAdd(total, wtot);
  base = __shfl(base, 63);
  int exc = base + sc - d;
  if (i < N){ start[i] = exc; cur[i] = exc; }
}

// scatter src ids into segment order; afterwards cur[node] == segment end
__global__ __launch_bounds__(256) void scatter_kernel(const int* __restrict__ src,
                                                      const int* __restrict__ dst,
                                                      int* __restrict__ cur,
                                                      int* __restrict__ srcs, int E){
  int e = blockIdx.x * 256 + threadIdx.x;
  if (e < E){
    int p = atomicAdd(&cur[dst[e]], 1);
    srcs[p] = src[e];
  }
}

// ---------------- per-layer: bf16 message table + column min/max ----------------
// m = relu(x)+eps rounded to bf16 (RNE); min/max taken over ROUNDED values so the
// softmax upper bound B stays exact. Positive floats: uint compare == float compare.

__global__ __launch_bounds__(256) void colminmax_kernel(
    const float* __restrict__ x, unsigned* __restrict__ mm,
    unsigned short* __restrict__ mh, int N){
  __shared__ unsigned smn[256], smx[256];
  int c = threadIdx.x & 63;
  int slot = blockIdx.x * 4 + (threadIdx.x >> 6);
  float mx = 0.f, mn = 1e30f;
  for (int r = slot; r < N; r += 256 * 4){
    float m = fmaxf(x[r * 64 + c], 0.f) + EPSM;
    unsigned u = __float_as_uint(m);
    u += 0x7FFFu + ((u >> 16) & 1u);         // round-to-nearest-even to bf16
    unsigned short us = (unsigned short)(u >> 16);
    mh[r * 64 + c] = us;
    float mb = __uint_as_float(((unsigned)us) << 16);
    mx = fmaxf(mx, mb);
    mn = fminf(mn, mb);
  }
  smn[threadIdx.x] = __float_as_uint(mn);
  smx[threadIdx.x] = __float_as_uint(mx);
  __syncthreads();
  if (threadIdx.x < 64){
    unsigned a = smn[c], b = smn[c + 64], d = smn[c + 128], e = smn[c + 192];
    unsigned mn4 = min(min(a, b), min(d, e));
    a = smx[c]; b = smx[c + 64]; d = smx[c + 128]; e = smx[c + 192];
    unsigned mx4 = max(max(a, b), max(d, e));
    atomicMin(&mm[c], mn4);
    atomicMax(&mm[64 + c], mx4);
  }
}

// ---------------- single-pass softmax aggregation, one wave per node ----------------
// exp(lg - B) with fixed per-channel B >= all logits: num/den ratio is exact.

__global__ __launch_bounds__(256) void aggregate_kernel(
    const float* __restrict__ x, const unsigned short* __restrict__ mh,
    const int* __restrict__ start, const int* __restrict__ segend,
    const int* __restrict__ srcs, const float* __restrict__ tptr, int layer,
    const unsigned* __restrict__ mm, float* __restrict__ h0, int N){
  int node = blockIdx.x * 4 + (threadIdx.x >> 6);
  if (node >= N) return;
  int c = threadIdx.x & 63;
  float t = tptr[layer];
  float mn = __uint_as_float(mm[c]);
  float mx = __uint_as_float(mm[64 + c]);
  float B = fmaxf(t * mx, t * mn);      // upper bound on logits (any sign of t)
  int beg = start[node], end = segend[node];
  float den0 = 0.f, den1 = 0.f, den2 = 0.f, den3 = 0.f;
  float num0 = 0.f, num1 = 0.f, num2 = 0.f, num3 = 0.f;
  int e = beg;
  for (; e + 4 <= end; e += 4){
    int s0 = srcs[e], s1 = srcs[e + 1], s2 = srcs[e + 2], s3 = srcs[e + 3];
    float m0 = __uint_as_float(((unsigned)mh[s0 * 64 + c]) << 16);
    float m1 = __uint_as_float(((unsigned)mh[s1 * 64 + c]) << 16);
    float m2 = __uint_as_float(((unsigned)mh[s2 * 64 + c]) << 16);
    float m3 = __uint_as_float(((unsigned)mh[s3 * 64 + c]) << 16);
    float e0 = __expf(m0 * t - B), e1 = __expf(m1 * t - B);
    float e2 = __expf(m2 * t - B), e3 = __expf(m3 * t - B);
    den0 += e0; num0 += m0 * e0;
    den1 += e1; num1 += m1 * e1;
    den2 += e2; num2 += m2 * e2;
    den3 += e3; num3 += m3 * e3;
  }
  for (; e < end; ++e){
    int s = srcs[e];
    float m = __uint_as_float(((unsigned)mh[s * 64 + c]) << 16);
    float ex = __expf(m * t - B);
    den0 += ex; num0 += m * ex;
  }
  float den = (den0 + den1) + (den2 + den3);
  float num = (num0 + num1) + (num2 + num3);
  h0[node * 64 + c] = num / (den + 1e-16f) + x[node * 64 + c];
}

// ---------------- MLP ----------------

// h1[N,128] = h0[N,64] @ W1[64,128] + b1 ; fused BN sum/sumsq accumulation
__global__ __launch_bounds__(256) void gemm1_kernel(
    const float* __restrict__ h0, const float* __restrict__ W1,
    const float* __restrict__ b1, float* __restrict__ h1,
    float* __restrict__ bn, int N){
  __shared__ float a_lds[64 * 68];
  __shared__ float w_lds[64 * 128];
  int t = threadIdx.x;
  const float4* wg = (const float4*)W1;
  float4* wl = (float4*)w_lds;
#pragma unroll
  for (int i = 0; i < 8; ++i) wl[t + 256 * i] = wg[t + 256 * i];
  int row0 = blockIdx.x * 64;
#pragma unroll
  for (int i = 0; i < 4; ++i){
    int li = t + 256 * i;
    int r = li >> 4, q = li & 15;
    int gr = row0 + r;
    float4 v = make_float4(0.f, 0.f, 0.f, 0.f);
    if (gr < N) v = ((const float4*)h0)[gr * 16 + q];
    *(float4*)&a_lds[r * 68 + q * 4] = v;
  }
  __syncthreads();
  int tc = t & 31, tr = t >> 5;
  float4 bias = ((const float4*)b1)[tc];
  float acc[8][4];
#pragma unroll
  for (int r = 0; r < 8; ++r){
    acc[r][0] = bias.x; acc[r][1] = bias.y; acc[r][2] = bias.z; acc[r][3] = bias.w;
  }
  for (int k = 0; k < 64; k += 4){
    float4 w0 = *(const float4*)&w_lds[(k + 0) * 128 + tc * 4];
    float4 w1 = *(const float4*)&w_lds[(k + 1) * 128 + tc * 4];
    float4 w2 = *(const float4*)&w_lds[(k + 2) * 128 + tc * 4];
    float4 w3 = *(const float4*)&w_lds[(k + 3) * 128 + tc * 4];
#pragma unroll
    for (int r = 0; r < 8; ++r){
      float4 a = *(const float4*)&a_lds[(tr * 8 + r) * 68 + k];
      acc[r][0] += a.x * w0.x + a.y * w1.x + a.z * w2.x + a.w * w3.x;
      acc[r][1] += a.x * w0.y + a.y * w1.y + a.z * w2.y + a.w * w3.y;
      acc[r][2] += a.x * w0.z + a.y * w1.z + a.z * w2.z + a.w * w3.z;
      acc[r][3] += a.x * w0.w + a.y * w1.w + a.z * w2.w + a.w * w3.w;
    }
  }
  float s[4] = {0.f, 0.f, 0.f, 0.f}, s2[4] = {0.f, 0.f, 0.f, 0.f};
#pragma unroll
  for (int r = 0; r < 8; ++r){
    int gr = row0 + tr * 8 + r;
    if (gr < N){
      *(float4*)&h1[gr * 128 + tc * 4] =
          make_float4(acc[r][0], acc[r][1], acc[r][2], acc[r][3]);
#pragma unroll
      for (int j = 0; j < 4; ++j){ s[j] += acc[r][j]; s2[j] += acc[r][j] * acc[r][j]; }
    }
  }
  __syncthreads();
  float* red = a_lds;
  if (t < 256){ red[t] = 0.f; }
  __syncthreads();
#pragma unroll
  for (int j = 0; j < 4; ++j){
    atomicAdd(&red[tc * 4 + j], s[j]);
    atomicAdd(&red[128 + tc * 4 + j], s2[j]);
  }
  __syncthreads();
  if (t < 256) atomicAdd(&bn[t], red[t]);
}

// xout = relu( relu(BN(h1)) @ W2 + b2 ) ; BN finalize + apply fused in preamble.
// Block 0 also seeds next layer's mm/bn buffers (double-buffered, safe).
__global__ __launch_bounds__(256) void gemm2_kernel(
    const float* __restrict__ h1, const float* __restrict__ bn,
    const float* __restrict__ gamma, const float* __restrict__ beta, int layer,
    const float* __restrict__ W2, const float* __restrict__ b2,
    float* __restrict__ xout, int N,
    unsigned* __restrict__ mm_next, float* __restrict__ bn_next){
  __shared__ float a_lds[64 * 132];
  __shared__ float w_lds[128 * 68];
  __shared__ float ss[256];     // scale[128], shift[128]
  int t = threadIdx.x;
  if (mm_next != 0 && blockIdx.x == 0){
    if (t < 64) mm_next[t] = 0x7F7FFFFFu;
    else if (t < 128) mm_next[t] = 0u;
    bn_next[t] = 0.f;
  }
  if (t < 128){
    float mean = bn[t] * (1.f / (float)N);
    float var = bn[128 + t] * (1.f / (float)N) - mean * mean;
    var = fmaxf(var, 0.f);
    float sc = gamma[layer * 128 + t] / sqrtf(var + BN_EPS);
    ss[t] = sc;
    ss[128 + t] = beta[layer * 128 + t] - mean * sc;
  }
  const float4* wg = (const float4*)W2;
#pragma unroll
  for (int i = 0; i < 8; ++i){
    int li = t + 256 * i;
    int k = li >> 4, q = li & 15;
    *(float4*)&w_lds[k * 68 + q * 4] = wg[li];
  }
  __syncthreads();
  int row0 = blockIdx.x * 64;
#pragma unroll
  for (int i = 0; i < 8; ++i){
    int li = t + 256 * i;
    int r = li >> 5, q = li & 31;
    int gr = row0 + r;
    float4 v = make_float4(0.f, 0.f, 0.f, 0.f);
    if (gr < N) v = ((const float4*)h1)[gr * 32 + q];
    float4 sc = *(const float4*)&ss[q * 4];
    float4 sh = *(const float4*)&ss[128 + q * 4];
    v.x = fmaxf(v.x * sc.x + sh.x, 0.f);
    v.y = fmaxf(v.y * sc.y + sh.y, 0.f);
    v.z = fmaxf(v.z * sc.z + sh.z, 0.f);
    v.w = fmaxf(v.w * sc.w + sh.w, 0.f);
    *(float4*)&a_lds[r * 132 + q * 4] = v;
  }
  __syncthreads();
  int tc = t & 15, tr = t >> 4;
  float4 bias = ((const float4*)b2)[tc];
  float acc[4][4];
#pragma unroll
  for (int r = 0; r < 4; ++r){
    acc[r][0] = bias.x; acc[r][1] = bias.y; acc[r][2] = bias.z; acc[r][3] = bias.w;
  }
  for (int k = 0; k < 128; k += 4){
    float4 w0 = *(const float4*)&w_lds[(k + 0) * 68 + tc * 4];
    float4 w1 = *(const float4*)&w_lds[(k + 1) * 68 + tc * 4];
    float4 w2 = *(const float4*)&w_lds[(k + 2) * 68 + tc * 4];
    float4 w3 = *(const float4*)&w_lds[(k + 3) * 68 + tc * 4];
#pragma unroll
    for (int r = 0; r < 4; ++r){
      float4 a = *(const float4*)&a_lds[(tr * 4 + r) * 132 + k];
      acc[r][0] += a.x * w0.x + a.y * w1.x + a.z * w2.x + a.w * w3.x;
      acc[r][1] += a.x * w0.y + a.y * w1.y + a.z * w2.y + a.w * w3.y;
      acc[r][2] += a.x * w0.z + a.y * w1.z + a.z * w2.z + a.w * w3.z;
      acc[r][3] += a.x * w0.w + a.y * w1.w + a.z * w2.w + a.w * w3.w;
    }
  }
#pragma unroll
  for (int r = 0; r < 4; ++r){
    int gr = row0 + tr * 4 + r;
    if (gr < N)
      *(float4*)&xout[gr * 64 + tc * 4] =
          make_float4(fmaxf(acc[r][0], 0.f), fmaxf(acc[r][1], 0.f),
                      fmaxf(acc[r][2], 0.f), fmaxf(acc[r][3], 0.f));
  }
}

extern "C" void kernel_launch(void* const* d_in, const int* in_sizes, int n_in,
                              void* d_out, int out_size, void* d_ws, size_t ws_size,
                              hipStream_t stream) {
  const float* x0    = (const float*)d_in[0];
  const int*   ei    = (const int*)d_in[1];
  const float* W1    = (const float*)d_in[2];
  const float* b1    = (const float*)d_in[3];
  const float* gamma = (const float*)d_in[4];
  const float* beta  = (const float*)d_in[5];
  const float* W2    = (const float*)d_in[6];
  const float* b2    = (const float*)d_in[7];
  const float* tptr  = (const float*)d_in[8];

  const int N = NN;
  const int E = in_sizes[1] / 2;
  const int* src = ei;
  const int* dst = ei + E;

  float* ws  = (float*)d_ws;
  float* h0  = ws;                        // N*64
  float* h1  = h0 + N * 64;               // N*128
  float* bn0 = h1 + N * 128;              // 256: sum|sumsq (layer 0)
  float* bn1 = bn0 + 256;                 // 256: layer 1
  unsigned* mm0 = (unsigned*)(bn1 + 256); // 128: colmin|colmax (layer 0)
  unsigned* mm1 = mm0 + 128;              // 128: layer 1
  unsigned short* mh = (unsigned short*)(mm1 + 128);  // N*64 bf16 messages
  int* deg   = (int*)(mh + N * 64);       // N
  int* total = deg + N;                   // 1
  int* start = total + 1;                 // N
  int* cur   = start + N;                 // N (segment end after scatter)
  int* srcs  = cur + N;                   // E

  float* out = (float*)d_out;

  const int row_blocks = (N + 63) / 64;
  const int edge_blocks = (E + 255) / 256;
  const int node_blocks = (N + 255) / 256;

  // ---- CSR build (edge structure is layer-invariant) ----
  hipMemsetAsync(deg, 0, (N + 1) * sizeof(int), stream);   // deg + total
  hist_kernel<<<edge_blocks, 256, 0, stream>>>(dst, deg, E, mm0, bn0);
  assign_kernel<<<node_blocks, 256, 0, stream>>>(deg, start, cur, total, N);
  scatter_kernel<<<edge_blocks, 256, 0, stream>>>(src, dst, cur, srcs, E);

  for (int l = 0; l < 2; ++l){
    const float* xin = (l == 0) ? x0 : out;
    unsigned* mm = (l == 0) ? mm0 : mm1;
    float* bn    = (l == 0) ? bn0 : bn1;
    colminmax_kernel<<<256, 256, 0, stream>>>(xin, mm, mh, N);
    aggregate_kernel<<<(N + 3) / 4, 256, 0, stream>>>(xin, mh, start, cur, srcs,
                                                      tptr, l, mm, h0, N);
    gemm1_kernel<<<row_blocks, 256, 0, stream>>>(h0, W1 + l * 8192, b1 + l * 128,
                                                 h1, bn, N);
    gemm2_kernel<<<row_blocks, 256, 0, stream>>>(h1, bn, gamma, beta, l,
                                                 W2 + l * 8192, b2 + l * 64, out, N,
                                                 (l == 0) ? mm1 : (unsigned*)0,
                                                 (l == 0) ? bn1 : (float*)0);
  }
}

// Round 6
// 341.305 us; speedup vs baseline: 3.6568x; 1.2209x over previous
//
#include <hip/hip_runtime.h>
#include <math.h>

#define NN 50000
#define EPSM 1e-7f
#define BN_EPS 1e-5f
#define NBK 391                 // ceil(50000/128) buckets of 128 nodes

// ---------------- bucket-sorted CSR build (line-coalesced writes) ----------------

// global bucket histogram via LDS pre-reduction; block 0 seeds layer-0 mm/bn
__global__ __launch_bounds__(256) void bucket_hist_kernel(
    const int* __restrict__ dst, int* __restrict__ bhist, int E,
    unsigned* __restrict__ mm0, float* __restrict__ bn0){
  __shared__ int h[NBK];
  int t = threadIdx.x;
  if (blockIdx.x == 0){
    if (t < 64) mm0[t] = 0x7F7FFFFFu;      // colmin seed = FLT_MAX
    else if (t < 128) mm0[t] = 0u;         // colmax seed = 0
    bn0[t] = 0.f;
  }
  for (int i = t; i < NBK; i += 256) h[i] = 0;
  __syncthreads();
  int e0 = blockIdx.x * 4096;
  int cnt = min(4096, E - e0);
  for (int i = t; i < cnt; i += 256) atomicAdd(&h[dst[e0 + i] >> 7], 1);
  __syncthreads();
  for (int i = t; i < NBK; i += 256) if (h[i]) atomicAdd(&bhist[i], h[i]);
}

// one-wave exclusive scan of 391 bucket counts -> bbase[392], gcur
__global__ void bucket_scan_kernel(const int* __restrict__ bhist,
                                   int* __restrict__ bbase, int* __restrict__ gcur){
  int lane = threadIdx.x;   // 64 threads
  int loc[7]; int s = 0;
#pragma unroll
  for (int k = 0; k < 7; ++k){
    int i = lane * 7 + k;
    int v = (i < NBK) ? bhist[i] : 0;
    loc[k] = s; s += v;
  }
  int sc = s;
#pragma unroll
  for (int o = 1; o < 64; o <<= 1){
    int n = __shfl_up(sc, o);
    if (lane >= o) sc += n;
  }
  int exc = sc - s;
#pragma unroll
  for (int k = 0; k < 7; ++k){
    int i = lane * 7 + k;
    if (i < NBK){ bbase[i] = exc + loc[k]; gcur[i] = exc + loc[k]; }
    else if (i == NBK) bbase[i] = exc + loc[k];   // total == E
  }
}

// pass 1: LDS-reorder 4096-edge chunks by bucket, burst-write packed (dst<<16|src)
__global__ __launch_bounds__(256) void bucket_scatter_kernel(
    const int* __restrict__ src, const int* __restrict__ dst,
    int* __restrict__ gcur, unsigned* __restrict__ packed_g, int E){
  __shared__ int hist[NBK], offs[NBK], gb[NBK], curk[NBK];
  __shared__ unsigned stage[4096];
  __shared__ int gpos[4096];
  int t = threadIdx.x;
  for (int i = t; i < NBK; i += 256) hist[i] = 0;
  __syncthreads();
  int e0 = blockIdx.x * 4096;
  int cnt = min(4096, E - e0);
  unsigned pk[16]; int bk[16];
  int nmine = 0;
  for (int i = t; i < cnt; i += 256){
    int d = dst[e0 + i], s = src[e0 + i];
    pk[nmine] = ((unsigned)d << 16) | (unsigned)s;
    bk[nmine] = d >> 7;
    atomicAdd(&hist[bk[nmine]], 1);
    ++nmine;
  }
  __syncthreads();
  if (t < 64){                      // wave-0 scan of 391 counts (7 per lane)
    int loc[7]; int s = 0;
#pragma unroll
    for (int k = 0; k < 7; ++k){
      int i = t * 7 + k;
      int v = (i < NBK) ? hist[i] : 0;
      loc[k] = s; s += v;
    }
    int sc = s;
#pragma unroll
    for (int o = 1; o < 64; o <<= 1){
      int n = __shfl_up(sc, o);
      if (t >= o) sc += n;
    }
    int exc = sc - s;
#pragma unroll
    for (int k = 0; k < 7; ++k){
      int i = t * 7 + k;
      if (i < NBK) offs[i] = exc + loc[k];
    }
  }
  __syncthreads();
  for (int i = t; i < NBK; i += 256){
    int h = hist[i];
    gb[i] = h ? atomicAdd(&gcur[i], h) : 0;
    curk[i] = offs[i];
  }
  __syncthreads();
  for (int k = 0; k < nmine; ++k){
    int b = bk[k];
    int p = atomicAdd(&curk[b], 1);
    stage[p] = pk[k];
    gpos[p] = gb[b] + (p - offs[b]);
  }
  __syncthreads();
  for (int j = t; j < cnt; j += 256) packed_g[gpos[j]] = stage[j];   // run-coalesced
}

// pass 2: one block per bucket — per-node offsets, start/end, coalesced srcs write
__global__ __launch_bounds__(256) void bucket_place_kernel(
    const unsigned* __restrict__ packed_g, const int* __restrict__ bbase,
    int* __restrict__ start_g, int* __restrict__ end_g,
    int* __restrict__ srcs_g, int N){
  __shared__ int deg[128], off[128], cur[128];
  __shared__ int sstage[4096];
  int b = blockIdx.x, t = threadIdx.x;
  int beg = bbase[b], cnt = bbase[b + 1] - beg;
  if (t < 128) deg[t] = 0;
  __syncthreads();
  for (int j = t; j < cnt; j += 256)
    atomicAdd(&deg[(packed_g[beg + j] >> 16) & 127], 1);
  __syncthreads();
  if (t < 64){                      // wave-0 scan of 128 (2 per lane)
    int i0 = t * 2;
    int v0 = deg[i0], v1 = deg[i0 + 1];
    int s = v0 + v1;
    int sc = s;
#pragma unroll
    for (int o = 1; o < 64; o <<= 1){
      int n = __shfl_up(sc, o);
      if (t >= o) sc += n;
    }
    int exc = sc - s;
    off[i0] = exc; off[i0 + 1] = exc + v0;
  }
  __syncthreads();
  int node0 = b * 128;
  if (t < 128){
    int node = node0 + t;
    if (node < N){
      start_g[node] = beg + off[t];
      end_g[node] = beg + off[t] + deg[t];
    }
    cur[t] = off[t];
  }
  __syncthreads();
  if (cnt <= 4096){
    for (int j = t; j < cnt; j += 256){
      unsigned p = packed_g[beg + j];
      int lp = atomicAdd(&cur[(p >> 16) & 127], 1);
      sstage[lp] = (int)(p & 0xFFFFu);
    }
    __syncthreads();
    for (int j = t; j < cnt; j += 256) srcs_g[beg + j] = sstage[j];  // coalesced
  } else {                          // freak-bucket fallback (never for random graph)
    for (int j = t; j < cnt; j += 256){
      unsigned p = packed_g[beg + j];
      int lp = atomicAdd(&cur[(p >> 16) & 127], 1);
      srcs_g[beg + lp] = (int)(p & 0xFFFFu);
    }
  }
}

// ---------------- layer-0 only: bf16 message table + column min/max ----------------

__global__ __launch_bounds__(256) void colminmax_kernel(
    const float* __restrict__ x, unsigned* __restrict__ mm,
    unsigned short* __restrict__ mh, int N){
  __shared__ unsigned smn[256], smx[256];
  int c = threadIdx.x & 63;
  int slot = blockIdx.x * 4 + (threadIdx.x >> 6);
  float mx = 0.f, mn = 1e30f;
  for (int r = slot; r < N; r += 256 * 4){
    float m = fmaxf(x[r * 64 + c], 0.f) + EPSM;
    unsigned u = __float_as_uint(m);
    u += 0x7FFFu + ((u >> 16) & 1u);         // RNE to bf16
    unsigned short us = (unsigned short)(u >> 16);
    mh[r * 64 + c] = us;
    float mb = __uint_as_float(((unsigned)us) << 16);
    mx = fmaxf(mx, mb);
    mn = fminf(mn, mb);
  }
  smn[threadIdx.x] = __float_as_uint(mn);
  smx[threadIdx.x] = __float_as_uint(mx);
  __syncthreads();
  if (threadIdx.x < 64){
    unsigned a = smn[c], b = smn[c + 64], d = smn[c + 128], e = smn[c + 192];
    atomicMin(&mm[c], min(min(a, b), min(d, e)));
    a = smx[c]; b = smx[c + 64]; d = smx[c + 128]; e = smx[c + 192];
    atomicMax(&mm[64 + c], max(max(a, b), max(d, e)));
  }
}

// ---------------- single-pass softmax aggregation, one wave per node ----------------

__global__ __launch_bounds__(256) void aggregate_kernel(
    const float* __restrict__ x, const unsigned short* __restrict__ mh,
    const int* __restrict__ start, const int* __restrict__ segend,
    const int* __restrict__ srcs, const float* __restrict__ tptr, int layer,
    const unsigned* __restrict__ mm, float* __restrict__ h0, int N){
  int node = blockIdx.x * 4 + (threadIdx.x >> 6);
  if (node >= N) return;
  int c = threadIdx.x & 63;
  float t = tptr[layer];
  float mn = __uint_as_float(mm[c]);
  float mx = __uint_as_float(mm[64 + c]);
  float B = fmaxf(t * mx, t * mn);      // upper bound on logits (any sign of t)
  int beg = start[node], end = segend[node];
  float den0 = 0.f, den1 = 0.f, den2 = 0.f, den3 = 0.f;
  float num0 = 0.f, num1 = 0.f, num2 = 0.f, num3 = 0.f;
  int e = beg;
  for (; e + 4 <= end; e += 4){
    int s0 = srcs[e], s1 = srcs[e + 1], s2 = srcs[e + 2], s3 = srcs[e + 3];
    float m0 = __uint_as_float(((unsigned)mh[s0 * 64 + c]) << 16);
    float m1 = __uint_as_float(((unsigned)mh[s1 * 64 + c]) << 16);
    float m2 = __uint_as_float(((unsigned)mh[s2 * 64 + c]) << 16);
    float m3 = __uint_as_float(((unsigned)mh[s3 * 64 + c]) << 16);
    float e0 = __expf(m0 * t - B), e1 = __expf(m1 * t - B);
    float e2 = __expf(m2 * t - B), e3 = __expf(m3 * t - B);
    den0 += e0; num0 += m0 * e0;
    den1 += e1; num1 += m1 * e1;
    den2 += e2; num2 += m2 * e2;
    den3 += e3; num3 += m3 * e3;
  }
  for (; e < end; ++e){
    int s = srcs[e];
    float m = __uint_as_float(((unsigned)mh[s * 64 + c]) << 16);
    float ex = __expf(m * t - B);
    den0 += ex; num0 += m * ex;
  }
  float den = (den0 + den1) + (den2 + den3);
  float num = (num0 + num1) + (num2 + num3);
  h0[node * 64 + c] = num / (den + 1e-16f) + x[node * 64 + c];
}

// ---------------- MLP ----------------

// h1 = h0 @ W1 + b1 ; fused BN sum/sumsq; layer-0 block 0 seeds next mm/bn
__global__ __launch_bounds__(256) void gemm1_kernel(
    const float* __restrict__ h0, const float* __restrict__ W1,
    const float* __restrict__ b1, float* __restrict__ h1,
    float* __restrict__ bn, int N,
    unsigned* __restrict__ mm_next, float* __restrict__ bn_next){
  __shared__ float a_lds[64 * 68];
  __shared__ float w_lds[64 * 128];
  int t = threadIdx.x;
  if (mm_next != 0 && blockIdx.x == 0){
    if (t < 64) mm_next[t] = 0x7F7FFFFFu;
    else if (t < 128) mm_next[t] = 0u;
    bn_next[t] = 0.f;
  }
  const float4* wg = (const float4*)W1;
  float4* wl = (float4*)w_lds;
#pragma unroll
  for (int i = 0; i < 8; ++i) wl[t + 256 * i] = wg[t + 256 * i];
  int row0 = blockIdx.x * 64;
#pragma unroll
  for (int i = 0; i < 4; ++i){
    int li = t + 256 * i;
    int r = li >> 4, q = li & 15;
    int gr = row0 + r;
    float4 v = make_float4(0.f, 0.f, 0.f, 0.f);
    if (gr < N) v = ((const float4*)h0)[gr * 16 + q];
    *(float4*)&a_lds[r * 68 + q * 4] = v;
  }
  __syncthreads();
  int tc = t & 31, tr = t >> 5;
  float4 bias = ((const float4*)b1)[tc];
  float acc[8][4];
#pragma unroll
  for (int r = 0; r < 8; ++r){
    acc[r][0] = bias.x; acc[r][1] = bias.y; acc[r][2] = bias.z; acc[r][3] = bias.w;
  }
  for (int k = 0; k < 64; k += 4){
    float4 w0 = *(const float4*)&w_lds[(k + 0) * 128 + tc * 4];
    float4 w1 = *(const float4*)&w_lds[(k + 1) * 128 + tc * 4];
    float4 w2 = *(const float4*)&w_lds[(k + 2) * 128 + tc * 4];
    float4 w3 = *(const float4*)&w_lds[(k + 3) * 128 + tc * 4];
#pragma unroll
    for (int r = 0; r < 8; ++r){
      float4 a = *(const float4*)&a_lds[(tr * 8 + r) * 68 + k];
      acc[r][0] += a.x * w0.x + a.y * w1.x + a.z * w2.x + a.w * w3.x;
      acc[r][1] += a.x * w0.y + a.y * w1.y + a.z * w2.y + a.w * w3.y;
      acc[r][2] += a.x * w0.z + a.y * w1.z + a.z * w2.z + a.w * w3.z;
      acc[r][3] += a.x * w0.w + a.y * w1.w + a.z * w2.w + a.w * w3.w;
    }
  }
  float s[4] = {0.f, 0.f, 0.f, 0.f}, s2[4] = {0.f, 0.f, 0.f, 0.f};
#pragma unroll
  for (int r = 0; r < 8; ++r){
    int gr = row0 + tr * 8 + r;
    if (gr < N){
      *(float4*)&h1[gr * 128 + tc * 4] =
          make_float4(acc[r][0], acc[r][1], acc[r][2], acc[r][3]);
#pragma unroll
      for (int j = 0; j < 4; ++j){ s[j] += acc[r][j]; s2[j] += acc[r][j] * acc[r][j]; }
    }
  }
  __syncthreads();
  float* red = a_lds;
  if (t < 256){ red[t] = 0.f; }
  __syncthreads();
#pragma unroll
  for (int j = 0; j < 4; ++j){
    atomicAdd(&red[tc * 4 + j], s[j]);
    atomicAdd(&red[128 + tc * 4 + j], s2[j]);
  }
  __syncthreads();
  if (t < 256) atomicAdd(&bn[t], red[t]);
}

// xout = relu( relu(BN(h1)) @ W2 + b2 ). Layer 0 also emits next layer's bf16
// message table (xout >= 0 so m = xout + eps) and column min/max into mm_next.
__global__ __launch_bounds__(256) void gemm2_kernel(
    const float* __restrict__ h1, const float* __restrict__ bn,
    const float* __restrict__ gamma, const float* __restrict__ beta, int layer,
    const float* __restrict__ W2, const float* __restrict__ b2,
    float* __restrict__ xout, int N,
    unsigned* __restrict__ mm_next, unsigned short* __restrict__ mh_next){
  __shared__ float a_lds[64 * 132];
  __shared__ float w_lds[128 * 68];
  __shared__ float ss[256];     // scale[128], shift[128]
  __shared__ unsigned smn[64], smx[64];
  int t = threadIdx.x;
  if (t < 128){
    float mean = bn[t] * (1.f / (float)N);
    float var = bn[128 + t] * (1.f / (float)N) - mean * mean;
    var = fmaxf(var, 0.f);
    float sc = gamma[layer * 128 + t] / sqrtf(var + BN_EPS);
    ss[t] = sc;
    ss[128 + t] = beta[layer * 128 + t] - mean * sc;
  }
  if (t < 64){ smn[t] = 0x7F7FFFFFu; smx[t] = 0u; }
  const float4* wg = (const float4*)W2;
#pragma unroll
  for (int i = 0; i < 8; ++i){
    int li = t + 256 * i;
    int k = li >> 4, q = li & 15;
    *(float4*)&w_lds[k * 68 + q * 4] = wg[li];
  }
  __syncthreads();
  int row0 = blockIdx.x * 64;
#pragma unroll
  for (int i = 0; i < 8; ++i){
    int li = t + 256 * i;
    int r = li >> 5, q = li & 31;
    int gr = row0 + r;
    float4 v = make_float4(0.f, 0.f, 0.f, 0.f);
    if (gr < N) v = ((const float4*)h1)[gr * 32 + q];
    float4 sc = *(const float4*)&ss[q * 4];
    float4 sh = *(const float4*)&ss[128 + q * 4];
    v.x = fmaxf(v.x * sc.x + sh.x, 0.f);
    v.y = fmaxf(v.y * sc.y + sh.y, 0.f);
    v.z = fmaxf(v.z * sc.z + sh.z, 0.f);
    v.w = fmaxf(v.w * sc.w + sh.w, 0.f);
    *(float4*)&a_lds[r * 132 + q * 4] = v;
  }
  __syncthreads();
  int tc = t & 15, tr = t >> 4;
  float4 bias = ((const float4*)b2)[tc];
  float acc[4][4];
#pragma unroll
  for (int r = 0; r < 4; ++r){
    acc[r][0] = bias.x; acc[r][1] = bias.y; acc[r][2] = bias.z; acc[r][3] = bias.w;
  }
  for (int k = 0; k < 128; k += 4){
    float4 w0 = *(const float4*)&w_lds[(k + 0) * 68 + tc * 4];
    float4 w1 = *(const float4*)&w_lds[(k + 1) * 68 + tc * 4];
    float4 w2 = *(const float4*)&w_lds[(k + 2) * 68 + tc * 4];
    float4 w3 = *(const float4*)&w_lds[(k + 3) * 68 + tc * 4];
#pragma unroll
    for (int r = 0; r < 4; ++r){
      float4 a = *(const float4*)&a_lds[(tr * 4 + r) * 132 + k];
      acc[r][0] += a.x * w0.x + a.y * w1.x + a.z * w2.x + a.w * w3.x;
      acc[r][1] += a.x * w0.y + a.y * w1.y + a.z * w2.y + a.w * w3.y;
      acc[r][2] += a.x * w0.z + a.y * w1.z + a.z * w2.z + a.w * w3.z;
      acc[r][3] += a.x * w0.w + a.y * w1.w + a.z * w2.w + a.w * w3.w;
    }
  }
  unsigned mnv[4] = {0x7F7FFFFFu, 0x7F7FFFFFu, 0x7F7FFFFFu, 0x7F7FFFFFu};
  unsigned mxv[4] = {0u, 0u, 0u, 0u};
#pragma unroll
  for (int r = 0; r < 4; ++r){
    int gr = row0 + tr * 4 + r;
    if (gr < N){
      float o0 = fmaxf(acc[r][0], 0.f), o1 = fmaxf(acc[r][1], 0.f);
      float o2 = fmaxf(acc[r][2], 0.f), o3 = fmaxf(acc[r][3], 0.f);
      *(float4*)&xout[gr * 64 + tc * 4] = make_float4(o0, o1, o2, o3);
      if (mh_next != 0){
        unsigned us[4];
        float ov[4] = {o0, o1, o2, o3};
#pragma unroll
        for (int j = 0; j < 4; ++j){
          unsigned u = __float_as_uint(ov[j] + EPSM);
          u += 0x7FFFu + ((u >> 16) & 1u);       // RNE to bf16
          us[j] = u >> 16;
          unsigned fb = us[j] << 16;              // rounded value bits (positive)
          mnv[j] = min(mnv[j], fb);
          mxv[j] = max(mxv[j], fb);
        }
        ((uint2*)mh_next)[gr * 16 + tc] =
            make_uint2(us[0] | (us[1] << 16), us[2] | (us[3] << 16));
      }
    }
  }
  if (mh_next != 0){
    __syncthreads();
#pragma unroll
    for (int j = 0; j < 4; ++j){
      atomicMin(&smn[tc * 4 + j], mnv[j]);
      atomicMax(&smx[tc * 4 + j], mxv[j]);
    }
    __syncthreads();
    if (t < 64){
      atomicMin(&mm_next[t], smn[t]);
      atomicMax(&mm_next[64 + t], smx[t]);
    }
  }
}

extern "C" void kernel_launch(void* const* d_in, const int* in_sizes, int n_in,
                              void* d_out, int out_size, void* d_ws, size_t ws_size,
                              hipStream_t stream) {
  const float* x0    = (const float*)d_in[0];
  const int*   ei    = (const int*)d_in[1];
  const float* W1    = (const float*)d_in[2];
  const float* b1    = (const float*)d_in[3];
  const float* gamma = (const float*)d_in[4];
  const float* beta  = (const float*)d_in[5];
  const float* W2    = (const float*)d_in[6];
  const float* b2    = (const float*)d_in[7];
  const float* tptr  = (const float*)d_in[8];

  const int N = NN;
  const int E = in_sizes[1] / 2;
  const int* src = ei;
  const int* dst = ei + E;

  float* ws  = (float*)d_ws;
  float* h0  = ws;                        // N*64
  float* h1  = h0 + N * 64;               // N*128
  float* bn0 = h1 + N * 128;              // 256
  float* bn1 = bn0 + 256;                 // 256
  unsigned* mm0 = (unsigned*)(bn1 + 256); // 128
  unsigned* mm1 = mm0 + 128;              // 128
  unsigned short* mh = (unsigned short*)(mm1 + 128);  // N*64 bf16 messages
  int* bhist = (int*)(mh + N * 64);       // NBK
  int* bbase = bhist + NBK;               // NBK+1
  int* gcur  = bbase + NBK + 1;           // NBK
  int* start = gcur + NBK;                // N
  int* segend = start + N;                // N
  unsigned* packed = (unsigned*)(segend + N);  // E
  int* srcs  = (int*)(packed + E);        // E

  float* out = (float*)d_out;

  const int row_blocks = (N + 63) / 64;
  const int chunk_blocks = (E + 4095) / 4096;

  // ---- bucket-sorted CSR build (edge structure is layer-invariant) ----
  hipMemsetAsync(bhist, 0, NBK * sizeof(int), stream);
  bucket_hist_kernel<<<chunk_blocks, 256, 0, stream>>>(dst, bhist, E, mm0, bn0);
  bucket_scan_kernel<<<1, 64, 0, stream>>>(bhist, bbase, gcur);
  bucket_scatter_kernel<<<chunk_blocks, 256, 0, stream>>>(src, dst, gcur, packed, E);
  bucket_place_kernel<<<NBK, 256, 0, stream>>>(packed, bbase, start, segend, srcs, N);

  // ---- layer 0 ----
  colminmax_kernel<<<256, 256, 0, stream>>>(x0, mm0, mh, N);
  aggregate_kernel<<<(N + 3) / 4, 256, 0, stream>>>(x0, mh, start, segend, srcs,
                                                    tptr, 0, mm0, h0, N);
  gemm1_kernel<<<row_blocks, 256, 0, stream>>>(h0, W1, b1, h1, bn0, N, mm1, bn1);
  gemm2_kernel<<<row_blocks, 256, 0, stream>>>(h1, bn0, gamma, beta, 0, W2, b2,
                                               out, N, mm1, mh);
  // ---- layer 1 ----
  aggregate_kernel<<<(N + 3) / 4, 256, 0, stream>>>(out, mh, start, segend, srcs,
                                                    tptr, 1, mm1, h0, N);
  gemm1_kernel<<<row_blocks, 256, 0, stream>>>(h0, W1 + 8192, b1 + 128, h1, bn1, N,
                                               (unsigned*)0, (float*)0);
  gemm2_kernel<<<row_blocks, 256, 0, stream>>>(h1, bn1, gamma, beta, 1, W2 + 8192,
                                               b2 + 64, out, N,
                                               (unsigned*)0, (unsigned short*)0);
}